// Round 1
// baseline (609.694 us; speedup 1.0000x reference)
//
#include <hip/hip_runtime.h>

// Equivariant linear: irreps [(32,1),(16,3),(8,5),(4,7)], DIM=148.
// out[n, off_b + v*d + i] = mul^-0.5 * sum_u x[n, off_b + u*d + i] * w_b[u*mul + v]
//
// v2 theory: previous kernel (full-row LDS staging, 37.9 KB/WG) was pinned at
// 1 wave/SIMD -> every latency fully exposed -> 19% of HBM BW. This version:
//  - loads x DIRECTLY per-lane (lane = row, strided f4 reads; L1 temporal reuse
//    gives full 64B-line utilization, so HBM traffic stays ideal)
//  - uses LDS only as a per-block store-coalescing buffer (13,312 B ->
//    12 WGs/CU = 3 waves/SIMD)
//  - software-pipelines: block b+1 loads issue before block b compute
//  - stores go acc -> padded LDS -> segmented coalesced f4 stores (avoids
//    partial-line RFO traffic that scattered 16B stores would cause)

#define ROWF 148   // floats per row
#define ROWS 64    // rows per workgroup (one 64-lane wave, lane = row)
#define LDSF 52    // padded LDS row stride in floats (max block: 48+4)

__device__ __forceinline__ float xc(const float4* v, int k) {
    // constexpr-indexed component access; stays in registers after unroll
    return ((const float*)v)[k];
}

template <int MUL, int D>
__device__ __forceinline__ void comp_blk(const float4* __restrict__ xin,
                                         const float* __restrict__ w,
                                         float scale,
                                         float4* __restrict__ aout) {
    constexpr int SZ  = MUL * D;
    constexpr int NF4 = SZ / 4;

    float acc[SZ];
#pragma unroll
    for (int k = 0; k < SZ; ++k) acc[k] = 0.0f;

#pragma unroll
    for (int u = 0; u < MUL; ++u) {
#pragma unroll
        for (int v = 0; v < MUL; ++v) {
            // w is a uniform kernel-arg pointer with constexpr index -> s_load
            float wv = w[u * MUL + v];
#pragma unroll
            for (int i = 0; i < D; ++i) {
                acc[v * D + i] += xc(xin, u * D + i) * wv;
            }
        }
    }

#pragma unroll
    for (int j = 0; j < NF4; ++j) {
        float4 o;
        o.x = acc[4 * j + 0] * scale;
        o.y = acc[4 * j + 1] * scale;
        o.z = acc[4 * j + 2] * scale;
        o.w = acc[4 * j + 3] * scale;
        aout[j] = o;
    }
}

// acc (per-lane row segment) -> padded LDS -> coalesced segmented f4 stores.
// PS in floats, PS % 8 == 4 so gcd(PS,32)==4 -> 8 lanes cover 32 banks on the
// b128 writes (conflict-light).
template <int NF4, int PS>
__device__ __forceinline__ void flush_store(const float4* __restrict__ a,
                                            float* __restrict__ lds, int lane,
                                            float* __restrict__ obase) {
    __syncthreads();  // 1-wave WG: cheap; fences prior block's LDS reads (WAR)
#pragma unroll
    for (int j = 0; j < NF4; ++j) {
        *(float4*)(lds + lane * PS + j * 4) = a[j];
    }
    __syncthreads();  // ds_writes visible to all lanes before cross-lane reads
#pragma unroll
    for (int k = 0; k < NF4; ++k) {
        const int f = k * 64 + lane;        // flat f4 index within block tile
        const int r = f / NF4;              // row (const divisor -> magic mul)
        const int c = f - r * NF4;          // chunk within row segment
        float4 v = *(const float4*)(lds + r * PS + c * 4);
        // consecutive lanes -> consecutive 16B within a row segment -> lines
        // are written whole (no read-for-ownership at L2)
        *(float4*)(obase + (size_t)r * ROWF + c * 4) = v;
    }
}

__global__ __launch_bounds__(64, 3) void eqlin_kernel(
    const float* __restrict__ x,
    const float* __restrict__ w0,
    const float* __restrict__ w1,
    const float* __restrict__ w2,
    const float* __restrict__ w3,
    float* __restrict__ out) {
    __shared__ float lds[ROWS * LDSF];  // 13,312 B -> 12 WGs/CU = 3 waves/SIMD

    const int lane = threadIdx.x;  // 0..63, one wave per WG, lane = row
    const size_t row = (size_t)blockIdx.x * ROWS + lane;
    const float* xr = x + row * ROWF;                       // 16B aligned (148%4==0)
    float* obase = out + (size_t)blockIdx.x * ROWS * ROWF;  // tile output base

    // ---- per-block x segments, loaded directly (per-lane strided f4) ----
    float4 xb0[8], xb1[12], xb2[10], xb3[7];
    {
        const float4* p = (const float4*)xr;  // block0: cols [0,32)
#pragma unroll
        for (int j = 0; j < 8; ++j) xb0[j] = p[j];
    }
    {
        const float4* p = (const float4*)(xr + 32);  // block1: cols [32,80)
#pragma unroll
        for (int j = 0; j < 12; ++j) xb1[j] = p[j];
    }

    float4 a[12];  // acc staging, reused per block (max NF4 = 12)

    // block0: 32x0e  (compute waits only on xb0's vmcnt; xb1 stays in flight)
    comp_blk<32, 1>(xb0, w0, 0.17677669529663687f, a);  // 32^-0.5
    flush_store<8, 36>(a, lds, lane, obase + 0);

    {
        const float4* p = (const float4*)(xr + 80);  // block2: cols [80,120)
#pragma unroll
        for (int j = 0; j < 10; ++j) xb2[j] = p[j];
    }

    // block1: 16x1o
    comp_blk<16, 3>(xb1, w1, 0.25f, a);                 // 16^-0.5
    flush_store<12, 52>(a, lds, lane, obase + 32);

    {
        const float4* p = (const float4*)(xr + 120);  // block3: cols [120,148)
#pragma unroll
        for (int j = 0; j < 7; ++j) xb3[j] = p[j];
    }

    // block2: 8x2e
    comp_blk<8, 5>(xb2, w2, 0.35355339059327373f, a);   // 8^-0.5
    flush_store<10, 44>(a, lds, lane, obase + 80);

    // block3: 4x3o
    comp_blk<4, 7>(xb3, w3, 0.5f, a);                   // 4^-0.5
    flush_store<7, 36>(a, lds, lane, obase + 120);
}

extern "C" void kernel_launch(void* const* d_in, const int* in_sizes, int n_in,
                              void* d_out, int out_size, void* d_ws, size_t ws_size,
                              hipStream_t stream) {
    const float* x  = (const float*)d_in[0];
    const float* w0 = (const float*)d_in[1];
    const float* w1 = (const float*)d_in[2];
    const float* w2 = (const float*)d_in[3];
    const float* w3 = (const float*)d_in[4];
    float* out = (float*)d_out;

    const int N = in_sizes[0] / ROWF;  // 524288
    const int tiles = N / ROWS;        // 8192 (exact)

    eqlin_kernel<<<dim3(tiles), dim3(64), 0, stream>>>(x, w0, w1, w2, w3, out);
}